// Round 18
// baseline (48.510 us; speedup 1.0000x reference)
//
#include <hip/hip_runtime.h>

#define Cc 8
#define Hh 128
#define Ww 128
#define Nn 64
#define Bb 8
#define Dd 169            // (C+2)*C + C + C*C + C + C + 1
#define HW (Hh * Ww)
#define QUADS 128         // 512 bn / 4 n's per quad
#define PXS 256           // px per stripe
#define NSTRIPE (HW / PXS)          // 64
#define NBLK (Bb * NSTRIPE * 4)     // 2048 blocks (4 quad-groups of 4)
#define FRAGW 32                    // u32 per lane per quad
#define FRAG_U32 (QUADS * 64 * FRAGW)
#define SLOTS 256                   // reduction slots per batch (64 stripes x 4 nq)

#define INV128 (1.0f / 128.0f)

typedef __fp16 f16x2 __attribute__((ext_vector_type(2)));
typedef _Float16 h8 __attribute__((ext_vector_type(8)));
typedef float f32x16 __attribute__((ext_vector_type(16)));

static __device__ __forceinline__ uint32_t pku(float a, float b) {
    f16x2 t = __builtin_amdgcn_cvt_pkrtz(a, b);
    uint32_t u; __builtin_memcpy(&u, &t, 4); return u;
}
static __device__ __forceinline__ f16x2 u2h(uint32_t u) {
    f16x2 r; __builtin_memcpy(&r, &u, 4); return r;
}
static __device__ __forceinline__ h8 u4h8(uint32_t a, uint32_t b, uint32_t c, uint32_t d) {
    uint32_t u[4] = {a, b, c, d}; h8 r; __builtin_memcpy(&r, u, 16); return r;
}

// ---- kernel A: per-lane 32x32 MFMA fragments per quad (4 n's) ----
// M rows 0..31 = 4 MLPs x 8. Shared bijection: slot s=(hi,e), hi=lane>>5.
// L1: slot(0,e)=seg ch e; slot(1,0)=x/128, slot(1,1)=y/128, slot(1,2)=1 (bias fold).
// L2: B2 slot(hi,e) holds h1 D-reg e -> h1 row r=(e&3)+8*(e>>2)+4hi; A2 matches.
//   A2a: e<8 covers rows 0-15 (MLPs 0,1); A2b: D regs 8-15 -> rows 16-31 (MLPs 2,3).
// Frag u32 slots: [0..3]A1 [4..7]A2a [8..11]A2b [12..19]b2C pairs (C/D-reg order)
//   [20..27] w3 pairs (m-major, lane's 4 channels 4hi..4hi+3) [28..29] b3 own f32
//   [30..31] m^2 own f32  (own m's = {2hi, 2hi+1})
__global__ void pack_frags(const float* __restrict__ conv_weight,
                           const float* __restrict__ mask,
                           const int*   __restrict__ ind,
                           uint32_t*    __restrict__ frag) {
    const int q   = blockIdx.x;          // 0..127
    const int b   = q >> 4;
    const int bn0 = b * Nn + (q & 15) * 4;
    const int l   = threadIdx.x;         // 0..63
    const int hi  = l >> 5, row = l & 31;
    const int m   = row >> 3, rr = row & 7;
    const float* base = conv_weight + (size_t)b * Dd * HW;
    const int ibm = ind[bn0 + m];
    const float* srcR = base + ibm;

    float a1[8];
    #pragma unroll
    for (int e = 0; e < 8; ++e) a1[e] = 0.f;
    if (hi == 0) {
        #pragma unroll
        for (int e = 0; e < 8; ++e) a1[e] = srcR[(size_t)(rr * 10 + e) * HW];
    } else {
        const float w8 = srcR[(size_t)(rr * 10 + 8) * HW];
        const float w9 = srcR[(size_t)(rr * 10 + 9) * HW];
        const float b1 = srcR[(size_t)(80 + rr) * HW];
        a1[0] = w8; a1[1] = w9;
        a1[2] = b1 - w8 * ((float)(ibm & 127) * INV128)
                   - w9 * ((float)(ibm >> 7) * INV128);
    }

    float a2a[8], a2b[8];
    #pragma unroll
    for (int e = 0; e < 8; ++e) {
        const int c = (e & 3) + 4 * hi;        // lane's channel for this slot
        float wv = 0.f;
        if ((e >> 2) == m || (e >> 2) + 2 == m)
            wv = srcR[(size_t)(88 + rr * 8 + c) * HW];
        a2a[e] = ((e >> 2) == m)     ? wv : 0.f;
        a2b[e] = ((e >> 2) + 2 == m) ? wv : 0.f;
    }

    // b2 in C/D-reg order: C[e] = b2[row(e,hi)], row = (e&3)+8*(e>>2)+4hi
    float b2r[16];
    #pragma unroll
    for (int e = 0; e < 16; ++e) {
        const int r  = (e & 3) + 8 * (e >> 2) + 4 * hi;
        const int mB = r >> 3, cB = r & 7;
        b2r[e] = (base + ind[bn0 + mB])[(size_t)(152 + cB) * HW];
    }
    // w3: per m, lane's channels 4hi+0..3
    float w3a[16];
    #pragma unroll
    for (int mm = 0; mm < 4; ++mm) {
        const float* s = base + ind[bn0 + mm];
        #pragma unroll
        for (int j = 0; j < 4; ++j)
            w3a[4 * mm + j] = s[(size_t)(160 + 4 * hi + j) * HW];
    }
    float b3o[2], flo[2];
    #pragma unroll
    for (int j = 0; j < 2; ++j) {
        const int mo = 2 * hi + j;
        b3o[j] = (base + ind[bn0 + mo])[(size_t)168 * HW];
        const float mm2 = mask[bn0 + mo];
        flo[j] = mm2 * mm2;
    }

    uint32_t* dst = frag + ((size_t)q * 64 + l) * FRAGW;
    dst[0] = pku(a1[0], a1[1]); dst[1] = pku(a1[2], a1[3]);
    dst[2] = pku(a1[4], a1[5]); dst[3] = pku(a1[6], a1[7]);
    dst[4] = pku(a2a[0], a2a[1]); dst[5] = pku(a2a[2], a2a[3]);
    dst[6] = pku(a2a[4], a2a[5]); dst[7] = pku(a2a[6], a2a[7]);
    dst[8] = pku(a2b[0], a2b[1]); dst[9] = pku(a2b[2], a2b[3]);
    dst[10] = pku(a2b[4], a2b[5]); dst[11] = pku(a2b[6], a2b[7]);
    #pragma unroll
    for (int j = 0; j < 8; ++j) dst[12 + j] = pku(b2r[2 * j], b2r[2 * j + 1]);
    #pragma unroll
    for (int j = 0; j < 8; ++j) dst[20 + j] = pku(w3a[2 * j], w3a[2 * j + 1]);
    float* df = (float*)dst;
    df[28] = b3o[0]; df[29] = b3o[1];
    df[30] = flo[0]; df[31] = flo[1];
}

// ---- kernel B: 32x32-MFMA main; B1 pre-staged in LDS; 4 quads per block ----
__global__ __launch_bounds__(256)
__attribute__((amdgpu_waves_per_eu(4, 8)))
void seg_dice_main(const float* __restrict__ seg_feat,
                   const float* __restrict__ target,
                   const uint32_t* __restrict__ frag,
                   float* __restrict__ red_base) {
    const int bid    = blockIdx.x;
    const int b      = bid & 7;
    const int rest   = bid >> 3;           // 0..255
    const int stripe = rest & 63;
    const int nq     = rest >> 6;          // 0..3
    const int p0     = stripe * PXS;
    const int tid  = threadIdx.x;
    const int wave = tid >> 6;
    const int l    = tid & 63;
    const int hi   = l >> 5, col = l & 31;

    __shared__ uint4 ldsB[8 * 64];         // [tile][hi][col] B1 fragments

    // stage B1 fragments: one px per thread
    {
        const int px = tid;                // 0..255
        const int gpx = p0 + px;
        const float* seg_b = seg_feat + (size_t)b * Cc * HW + gpx;
        float v[8];
        #pragma unroll
        for (int c = 0; c < 8; ++c) v[c] = seg_b[(size_t)c * HW];
        const int tc = (px >> 5) * 64 + (px & 31);
        ldsB[tc]      = uint4{pku(v[0], v[1]), pku(v[2], v[3]),
                              pku(v[4], v[5]), pku(v[6], v[7])};
        ldsB[tc + 32] = uint4{pku((float)(gpx & 127) * INV128,
                                  (float)(gpx >> 7) * INV128),
                              pku(1.f, 0.f), 0u, 0u};
    }
    __syncthreads();

    float inter = 0.f, ps = 0.f, ts = 0.f;

    #pragma unroll 1
    for (int it = 0; it < 4; ++it) {
        const int ql   = nq * 4 + it;                  // quad within b
        const int bn0q = b * Nn + ql * 4;
        const uint4* fp = (const uint4*)(frag + (((size_t)(b * 16 + ql)) * 64 + l) * FRAGW);
        const uint4 q0 = fp[0], q1 = fp[1], q2 = fp[2], q3 = fp[3];
        const uint4 q4 = fp[4], q5 = fp[5], q6 = fp[6], q7 = fp[7];

        const h8 A1h  = u4h8(q0.x, q0.y, q0.z, q0.w);
        const h8 A2ah = u4h8(q1.x, q1.y, q1.z, q1.w);
        const h8 A2bh = u4h8(q2.x, q2.y, q2.z, q2.w);

        f32x16 C2f;
        {
            const uint32_t pr[8] = {q3.x, q3.y, q3.z, q3.w, q4.x, q4.y, q4.z, q4.w};
            #pragma unroll
            for (int j = 0; j < 8; ++j) {
                const f16x2 v = u2h(pr[j]);
                C2f[2 * j]     = (float)v.x;
                C2f[2 * j + 1] = (float)v.y;
            }
        }
        float w3f[16];
        {
            const uint32_t pr[8] = {q5.x, q5.y, q5.z, q5.w, q6.x, q6.y, q6.z, q6.w};
            #pragma unroll
            for (int j = 0; j < 8; ++j) {
                const f16x2 v = u2h(pr[j]);
                w3f[2 * j]     = (float)v.x;
                w3f[2 * j + 1] = (float)v.y;
            }
        }
        const float b3_0 = __uint_as_float(q7.x);
        const float b3_1 = __uint_as_float(q7.y);
        const float fl_0 = __uint_as_float(q7.z);
        const float fl_1 = __uint_as_float(q7.w);
        const float* t0 = target + (size_t)(bn0q + 2 * hi) * HW + p0 + col;
        const float* t1 = t0 + HW;

        #pragma unroll 1
        for (int tile = wave; tile < 8; tile += 4) {
            const uint4 bq = ldsB[tile * 64 + hi * 32 + col];
            const h8 B1 = u4h8(bq.x, bq.y, bq.z, bq.w);
            const float tv0 = t0[tile * 32];
            const float tv1 = t1[tile * 32];

            const f32x16 ZF = {};
            f32x16 D1 = __builtin_amdgcn_mfma_f32_32x32x16_f16(A1h, B1, ZF, 0, 0, 0);
            #pragma unroll
            for (int e = 0; e < 16; ++e) D1[e] = fmaxf(D1[e], 0.f);

            const h8 B2a = u4h8(pku(D1[0], D1[1]), pku(D1[2], D1[3]),
                                pku(D1[4], D1[5]), pku(D1[6], D1[7]));
            const h8 B2b = u4h8(pku(D1[8], D1[9]), pku(D1[10], D1[11]),
                                pku(D1[12], D1[13]), pku(D1[14], D1[15]));
            f32x16 T  = __builtin_amdgcn_mfma_f32_32x32x16_f16(A2ah, B2a, C2f, 0, 0, 0);
            f32x16 H2 = __builtin_amdgcn_mfma_f32_32x32x16_f16(A2bh, B2b, T, 0, 0, 0);

            // z partials per MLP m over lane's 4 channels
            float zp0 = fmaxf(H2[0], 0.f) * w3f[0];
            zp0 = fmaf(fmaxf(H2[1], 0.f), w3f[1], zp0);
            zp0 = fmaf(fmaxf(H2[2], 0.f), w3f[2], zp0);
            zp0 = fmaf(fmaxf(H2[3], 0.f), w3f[3], zp0);
            float zp1 = fmaxf(H2[4], 0.f) * w3f[4];
            zp1 = fmaf(fmaxf(H2[5], 0.f), w3f[5], zp1);
            zp1 = fmaf(fmaxf(H2[6], 0.f), w3f[6], zp1);
            zp1 = fmaf(fmaxf(H2[7], 0.f), w3f[7], zp1);
            float zp2 = fmaxf(H2[8], 0.f) * w3f[8];
            zp2 = fmaf(fmaxf(H2[9], 0.f), w3f[9], zp2);
            zp2 = fmaf(fmaxf(H2[10], 0.f), w3f[10], zp2);
            zp2 = fmaf(fmaxf(H2[11], 0.f), w3f[11], zp2);
            float zp3 = fmaxf(H2[12], 0.f) * w3f[12];
            zp3 = fmaf(fmaxf(H2[13], 0.f), w3f[13], zp3);
            zp3 = fmaf(fmaxf(H2[14], 0.f), w3f[14], zp3);
            zp3 = fmaf(fmaxf(H2[15], 0.f), w3f[15], zp3);

            // parity exchange: send the partials of the PARTNER's owned m's
            const float s0 = hi ? zp0 : zp2;
            const float s1 = hi ? zp1 : zp3;
            const float r0 = __shfl_xor(s0, 32);
            const float r1 = __shfl_xor(s1, 32);
            const float z0 = (hi ? zp2 : zp0) + r0 + b3_0;
            const float z1 = (hi ? zp3 : zp1) + r1 + b3_1;

            const float o0 = __builtin_amdgcn_rcpf(1.f + __expf(-z0));
            const float o1 = __builtin_amdgcn_rcpf(1.f + __expf(-z1));
            const float fo0 = fl_0 * o0;
            const float fo1 = fl_1 * o1;
            inter = fmaf(fo0, tv0, inter);
            inter = fmaf(fo1, tv1, inter);
            ps    = fmaf(fo0, o0, ps);
            ps    = fmaf(fo1, o1, ps);
            ts    = fmaf(fl_0, tv0 * tv0, ts);
            ts    = fmaf(fl_1, tv1 * tv1, ts);
        }
    }

    // wave reduce then cross-wave
    #pragma unroll
    for (int off = 32; off > 0; off >>= 1) {
        inter += __shfl_down(inter, off);
        ps    += __shfl_down(ps,    off);
        ts    += __shfl_down(ts,    off);
    }
    __shared__ float red[3][4];
    if ((tid & 63) == 0) { red[0][wave] = inter; red[1][wave] = ps; red[2][wave] = ts; }
    __syncthreads();
    if (tid == 0) {
        red_base[(b * 3 + 0) * SLOTS + rest] = red[0][0] + red[0][1] + red[0][2] + red[0][3];
        red_base[(b * 3 + 1) * SLOTS + rest] = red[1][0] + red[1][1] + red[1][2] + red[1][3];
        red_base[(b * 3 + 2) * SLOTS + rest] = red[2][0] + red[2][1] + red[2][2] + red[2][3];
    }
}

// deterministic epilogue: 24 series x 256 partials
__global__ void seg_dice_final(const float* __restrict__ red_base, float* __restrict__ out) {
    __shared__ float red[24][4];
    const int tid = threadIdx.x;  // 128 threads
    if (tid < 96) {
        const int series = tid >> 2;
        const int part   = tid & 3;
        const float4* p = (const float4*)(red_base + series * SLOTS + part * 64);
        float s = 0.f;
        #pragma unroll
        for (int i = 0; i < 16; ++i) { const float4 v = p[i]; s += (v.x + v.y) + (v.z + v.w); }
        red[series][part] = s;
    }
    __syncthreads();
    if (tid == 0) {
        float acc = 0.f;
        #pragma unroll
        for (int b = 0; b < Bb; ++b) {
            const float inter = red[b*3+0][0] + red[b*3+0][1] + red[b*3+0][2] + red[b*3+0][3];
            const float p2    = red[b*3+1][0] + red[b*3+1][1] + red[b*3+1][2] + red[b*3+1][3];
            const float t2    = red[b*3+2][0] + red[b*3+2][1] + red[b*3+2][2] + red[b*3+2][3];
            acc += 1.0f - (2.0f * inter + 1.0f) / (p2 + t2 + 1.0f);
        }
        out[0] = acc * (1.0f / (float)Bb);
    }
}

extern "C" void kernel_launch(void* const* d_in, const int* in_sizes, int n_in,
                              void* d_out, int out_size, void* d_ws, size_t ws_size,
                              hipStream_t stream) {
    const float* seg_feat    = (const float*)d_in[0];
    const float* conv_weight = (const float*)d_in[1];
    const float* mask        = (const float*)d_in[2];
    const int*   ind         = (const int*)d_in[3];
    const float* target      = (const float*)d_in[4];
    float* out = (float*)d_out;

    uint32_t* fragtab  = (uint32_t*)d_ws;
    float*    red_base = (float*)d_ws + FRAG_U32;

    pack_frags<<<QUADS, 64, 0, stream>>>(conv_weight, mask, ind, fragtab);
    seg_dice_main<<<NBLK, 256, 0, stream>>>(seg_feat, target, fragtab, red_base);
    seg_dice_final<<<1, 128, 0, stream>>>(red_base, out);
}

// Round 19
// 35.241 us; speedup vs baseline: 1.3765x; 1.3765x over previous
//
#include <hip/hip_runtime.h>

#define Cc 8
#define Hh 128
#define Ww 128
#define Nn 64
#define Bb 8
#define Dd 169            // (C+2)*C + C + C*C + C + C + 1
#define HW (Hh * Ww)
#define NP 2              // n-pairs per block (4 n's)
#define NPG 16            // n-pair groups per batch (32/NP)
#define PXS 1024          // pixels per stripe (block)
#define NSTRIPE (HW / PXS)          // 16
#define NBLK (Bb * NPG * NSTRIPE)   // 2048 blocks
#define FRAGW 16                    // u32 per lane per n-pair in frag table
#define FRAG_U32 (256 * 64 * FRAGW) // 256 n-pairs total
#define SLOTS (NPG * NSTRIPE)       // 256 reduction slots per batch

#define INV128 (1.0f / 128.0f)

typedef __fp16 f16x2 __attribute__((ext_vector_type(2)));
typedef _Float16 h8 __attribute__((ext_vector_type(8)));
typedef float f32x4 __attribute__((ext_vector_type(4)));

static __device__ __forceinline__ uint32_t pku(float a, float b) {
    f16x2 t = __builtin_amdgcn_cvt_pkrtz(a, b);
    uint32_t u; __builtin_memcpy(&u, &t, 4); return u;
}
static __device__ __forceinline__ h8 u4h8(uint32_t a, uint32_t b, uint32_t c, uint32_t d) {
    uint32_t u[4] = {a, b, c, d}; h8 r; __builtin_memcpy(&r, u, 16); return r;
}

// ---- kernel A: per-lane MFMA fragments per n-pair (r16/r17 layout, validated) ----
// L1 k = 8g+e (k10 = const-1 carrying bias + x0/y0 fold). L2 k2 = 4g+e, plus
// bias slot: B2 elem4 on g==0 = 1.0, A2 elem4 (g==0) = b2[row].
// Slots/lane: [0..3]=A1, [4..6]=A2(+bias), [7..10]=w3 f32, [11]=b3, [12]=m^2
__global__ void pack_frags(const float* __restrict__ conv_weight,
                           const float* __restrict__ mask,
                           const int*   __restrict__ ind,
                           uint32_t*    __restrict__ frag) {
    const int npair = blockIdx.x;            // 0..255
    const int b     = npair >> 5;
    const int bn0   = b * Nn + 2 * (npair & 31);
    const int l  = threadIdx.x;              // 0..63
    const int g  = l >> 4, r = l & 15, rr = r & 7;
    const int bnr = bn0 + (r >> 3);          // row-owner n
    const int bng = bn0 + (g >> 1);          // D-row-group owner n
    const float* base = conv_weight + (size_t)b * Dd * HW;
    const float* srcR = base + ind[bnr];
    const float* srcG = base + ind[bng];

    float a1[8];
    #pragma unroll
    for (int e = 0; e < 8; ++e) {
        const int k = 8 * g + e;
        float v = 0.f;
        if (k < 8)       v = srcR[(size_t)(rr * 10 + k) * HW];
        else if (k == 8) v = srcR[(size_t)(rr * 10 + 8) * HW];
        else if (k == 9) v = srcR[(size_t)(rr * 10 + 9) * HW];
        else if (k == 10) {
            const float w8 = srcR[(size_t)(rr * 10 + 8) * HW];
            const float w9 = srcR[(size_t)(rr * 10 + 9) * HW];
            const float b1 = srcR[(size_t)(80 + rr) * HW];
            const int   ib = ind[bnr];
            v = b1 - w8 * ((float)(ib & 127) * INV128)
                   - w9 * ((float)(ib >> 7) * INV128);
        }
        a1[e] = v;
    }
    float a2[4];
    #pragma unroll
    for (int e = 0; e < 4; ++e) {
        const int k2 = 4 * g + e;
        float v = 0.f;
        if (r < 8)  { if (k2 < 8)  v = srcR[(size_t)(88 + rr * 8 + k2) * HW]; }
        else        { if (k2 >= 8) v = srcR[(size_t)(88 + rr * 8 + (k2 - 8)) * HW]; }
        a2[e] = v;
    }
    const float b2bias = (g == 0) ? srcR[(size_t)(152 + rr) * HW] : 0.f;

    float w3v[4];
    #pragma unroll
    for (int j = 0; j < 4; ++j) {
        const int c = (4 * g + j) & 7;
        w3v[j] = srcG[(size_t)(160 + c) * HW];
    }
    const float b3 = srcG[(size_t)168 * HW];
    const float mm = mask[bng];

    uint32_t* dst = frag + ((size_t)npair * 64 + l) * FRAGW;
    dst[0] = pku(a1[0], a1[1]); dst[1] = pku(a1[2], a1[3]);
    dst[2] = pku(a1[4], a1[5]); dst[3] = pku(a1[6], a1[7]);
    dst[4] = pku(a2[0], a2[1]); dst[5] = pku(a2[2], a2[3]);
    dst[6] = pku(b2bias, 0.f);
    float* df = (float*)dst;
    df[7] = w3v[0]; df[8] = w3v[1]; df[9] = w3v[2]; df[10] = w3v[3];
    df[11] = b3; df[12] = mm * mm;
    dst[13] = 0u; dst[14] = 0u; dst[15] = 0u;
}

// ---- kernel B: r17 + 2-way software pipeline (tiles tt, tt+4 interleaved) ----
__global__ __launch_bounds__(256)
__attribute__((amdgpu_waves_per_eu(4, 8)))
void seg_dice_main(const float* __restrict__ seg_feat,
                   const float* __restrict__ target,
                   const uint32_t* __restrict__ frag,
                   float* __restrict__ red_base) {
    const int bid    = blockIdx.x;
    const int b      = bid & 7;
    const int rest   = bid >> 3;           // 0..255
    const int npg    = rest & 15;
    const int stripe = rest >> 4;          // 0..15
    const int p0     = stripe * PXS;
    const int tid  = threadIdx.x;
    const int wave = tid >> 6;
    const int l    = tid & 63;
    const int g    = l >> 4, col = l & 15;

    __shared__ uint4 lds4[PXS];            // pixel-major seg tile: 8 f16/px

    const float* seg_b = seg_feat + (size_t)b * Cc * HW;
    #pragma unroll
    for (int q = 0; q < 4; ++q) {
        const int px = q * 256 + tid;
        float v[8];
        #pragma unroll
        for (int c = 0; c < 8; ++c) v[c] = seg_b[(size_t)c * HW + p0 + px];
        lds4[px] = uint4{pku(v[0], v[1]), pku(v[2], v[3]),
                         pku(v[4], v[5]), pku(v[6], v[7])};
    }

    // per-lane fragments for the 2 n-pairs; A-operands built ONCE as h8
    const int npair0 = b * 32 + npg * NP;
    const int par = g & 1;
    h8 A1h[NP], A2h[NP];
    float w3v[NP][4];
    float flS = 0.f, b3S = 0.f;
    const float* ptrS = target;
    #pragma unroll
    for (int j = 0; j < NP; ++j) {
        const uint4* fp = (const uint4*)(frag + ((size_t)(npair0 + j) * 64 + l) * FRAGW);
        const uint4 q0 = fp[0], q1 = fp[1], q2 = fp[2];
        const uint32_t q3x = ((const uint32_t*)fp)[12];
        A1h[j] = u4h8(q0.x, q0.y, q0.z, q0.w);
        A2h[j] = u4h8(q1.x, q1.y, q1.z, 0u);
        w3v[j][0] = __uint_as_float(q1.w);
        w3v[j][1] = __uint_as_float(q2.x);
        w3v[j][2] = __uint_as_float(q2.y);
        w3v[j][3] = __uint_as_float(q2.z);
        if (j == par) {
            b3S = __uint_as_float(q2.w);
            flS = __uint_as_float(q3x);
            const int bnS = b * Nn + 2 * (npg * NP + j) + (l >> 5);
            ptrS = target + (size_t)bnS * HW + p0 + col;
        }
    }
    __syncthreads();

    const uint32_t one16 = 0x3C00u;
    const uint32_t b2one = (g == 0) ? one16 : 0u;
    const f32x4 ZF = {0.f, 0.f, 0.f, 0.f};
    float inter = 0.f, ps = 0.f, ts = 0.f;

    #pragma unroll 1
    for (int tt = wave; tt < 64; tt += 8) {
        const int pu = tt * 16;            // tile u
        const int pv = pu + 64;            // tile v = tt+4
        const int pxgu = p0 + pu + col;
        const int pxgv = p0 + pv + col;

        // ---- issue ALL memory for both tiles up front ----
        const float tvu = ptrS[pu];
        const float tvv = ptrS[pv];
        const uint4 du = lds4[pu + col];
        const uint4 dv = lds4[pv + col];

        // ---- B1 build (u, v) ----
        const uint32_t xvu = pku((float)(pxgu & 127) * INV128,
                                 (float)(pxgu >> 7) * INV128);
        const uint32_t xvv = pku((float)(pxgv & 127) * INV128,
                                 (float)(pxgv >> 7) * INV128);
        const h8 B1u = u4h8((g == 0) ? du.x : ((g == 1) ? xvu : 0u),
                            (g == 0) ? du.y : ((g == 1) ? one16 : 0u),
                            (g == 0) ? du.z : 0u,
                            (g == 0) ? du.w : 0u);
        const h8 B1v = u4h8((g == 0) ? dv.x : ((g == 1) ? xvv : 0u),
                            (g == 0) ? dv.y : ((g == 1) ? one16 : 0u),
                            (g == 0) ? dv.z : 0u,
                            (g == 0) ? dv.w : 0u);

        // ---- L1 MFMAs: 4 independent ----
        f32x4 h1au = __builtin_amdgcn_mfma_f32_16x16x32_f16(A1h[0], B1u, ZF, 0, 0, 0);
        f32x4 h1bu = __builtin_amdgcn_mfma_f32_16x16x32_f16(A1h[1], B1u, ZF, 0, 0, 0);
        f32x4 h1av = __builtin_amdgcn_mfma_f32_16x16x32_f16(A1h[0], B1v, ZF, 0, 0, 0);
        f32x4 h1bv = __builtin_amdgcn_mfma_f32_16x16x32_f16(A1h[1], B1v, ZF, 0, 0, 0);
        #pragma unroll
        for (int e = 0; e < 4; ++e) {
            h1au[e] = fmaxf(h1au[e], 0.f); h1bu[e] = fmaxf(h1bu[e], 0.f);
            h1av[e] = fmaxf(h1av[e], 0.f); h1bv[e] = fmaxf(h1bv[e], 0.f);
        }
        const h8 B2au = u4h8(pku(h1au[0], h1au[1]), pku(h1au[2], h1au[3]), b2one, 0u);
        const h8 B2bu = u4h8(pku(h1bu[0], h1bu[1]), pku(h1bu[2], h1bu[3]), b2one, 0u);
        const h8 B2av = u4h8(pku(h1av[0], h1av[1]), pku(h1av[2], h1av[3]), b2one, 0u);
        const h8 B2bv = u4h8(pku(h1bv[0], h1bv[1]), pku(h1bv[2], h1bv[3]), b2one, 0u);

        // ---- L2 MFMAs: 4 independent ----
        f32x4 h2au = __builtin_amdgcn_mfma_f32_16x16x32_f16(A2h[0], B2au, ZF, 0, 0, 0);
        f32x4 h2bu = __builtin_amdgcn_mfma_f32_16x16x32_f16(A2h[1], B2bu, ZF, 0, 0, 0);
        f32x4 h2av = __builtin_amdgcn_mfma_f32_16x16x32_f16(A2h[0], B2av, ZF, 0, 0, 0);
        f32x4 h2bv = __builtin_amdgcn_mfma_f32_16x16x32_f16(A2h[1], B2bv, ZF, 0, 0, 0);

        // ---- z dot products (u, v interleaved) ----
        float zpau = fmaxf(h2au[0], 0.f) * w3v[0][0];
        float zpav = fmaxf(h2av[0], 0.f) * w3v[0][0];
        zpau = fmaf(fmaxf(h2au[1], 0.f), w3v[0][1], zpau);
        zpav = fmaf(fmaxf(h2av[1], 0.f), w3v[0][1], zpav);
        zpau = fmaf(fmaxf(h2au[2], 0.f), w3v[0][2], zpau);
        zpav = fmaf(fmaxf(h2av[2], 0.f), w3v[0][2], zpav);
        zpau = fmaf(fmaxf(h2au[3], 0.f), w3v[0][3], zpau);
        zpav = fmaf(fmaxf(h2av[3], 0.f), w3v[0][3], zpav);
        float zpbu = fmaxf(h2bu[0], 0.f) * w3v[1][0];
        float zpbv = fmaxf(h2bv[0], 0.f) * w3v[1][0];
        zpbu = fmaf(fmaxf(h2bu[1], 0.f), w3v[1][1], zpbu);
        zpbv = fmaf(fmaxf(h2bv[1], 0.f), w3v[1][1], zpbv);
        zpbu = fmaf(fmaxf(h2bu[2], 0.f), w3v[1][2], zpbu);
        zpbv = fmaf(fmaxf(h2bv[2], 0.f), w3v[1][2], zpbv);
        zpbu = fmaf(fmaxf(h2bu[3], 0.f), w3v[1][3], zpbu);
        zpbv = fmaf(fmaxf(h2bv[3], 0.f), w3v[1][3], zpbv);

        // ---- cross-half reduce: 4 shfls, two independent pairs ----
        zpau += __shfl_xor(zpau, 16);
        zpav += __shfl_xor(zpav, 16);
        zpbu += __shfl_xor(zpbu, 16);
        zpbv += __shfl_xor(zpbv, 16);

        // ---- sigmoid + dice (u, v) ----
        const float zu = (par ? zpbu : zpau) + b3S;
        const float zv = (par ? zpbv : zpav) + b3S;
        const float ou = __builtin_amdgcn_rcpf(1.f + __expf(-zu));
        const float ov = __builtin_amdgcn_rcpf(1.f + __expf(-zv));
        const float fou = flS * ou;
        const float fov = flS * ov;
        inter = fmaf(fou, tvu, inter);
        inter = fmaf(fov, tvv, inter);
        ps    = fmaf(fou, ou, ps);
        ps    = fmaf(fov, ov, ps);
        ts    = fmaf(flS, tvu * tvu, ts);
        ts    = fmaf(flS, tvv * tvv, ts);
    }

    // wave reduce then cross-wave
    #pragma unroll
    for (int off = 32; off > 0; off >>= 1) {
        inter += __shfl_down(inter, off);
        ps    += __shfl_down(ps,    off);
        ts    += __shfl_down(ts,    off);
    }
    __shared__ float red[3][4];
    if ((tid & 63) == 0) { red[0][wave] = inter; red[1][wave] = ps; red[2][wave] = ts; }
    __syncthreads();
    if (tid == 0) {
        red_base[(b * 3 + 0) * SLOTS + rest] = red[0][0] + red[0][1] + red[0][2] + red[0][3];
        red_base[(b * 3 + 1) * SLOTS + rest] = red[1][0] + red[1][1] + red[1][2] + red[1][3];
        red_base[(b * 3 + 2) * SLOTS + rest] = red[2][0] + red[2][1] + red[2][2] + red[2][3];
    }
}

// deterministic epilogue: 24 series x 256 partials
__global__ void seg_dice_final(const float* __restrict__ red_base, float* __restrict__ out) {
    __shared__ float red[24][4];
    const int tid = threadIdx.x;  // 128 threads
    if (tid < 96) {
        const int series = tid >> 2;
        const int part   = tid & 3;
        const float4* p = (const float4*)(red_base + series * SLOTS + part * 64);
        float s = 0.f;
        #pragma unroll
        for (int i = 0; i < 16; ++i) { const float4 v = p[i]; s += (v.x + v.y) + (v.z + v.w); }
        red[series][part] = s;
    }
    __syncthreads();
    if (tid == 0) {
        float acc = 0.f;
        #pragma unroll
        for (int b = 0; b < Bb; ++b) {
            const float inter = red[b*3+0][0] + red[b*3+0][1] + red[b*3+0][2] + red[b*3+0][3];
            const float p2    = red[b*3+1][0] + red[b*3+1][1] + red[b*3+1][2] + red[b*3+1][3];
            const float t2    = red[b*3+2][0] + red[b*3+2][1] + red[b*3+2][2] + red[b*3+2][3];
            acc += 1.0f - (2.0f * inter + 1.0f) / (p2 + t2 + 1.0f);
        }
        out[0] = acc * (1.0f / (float)Bb);
    }
}

extern "C" void kernel_launch(void* const* d_in, const int* in_sizes, int n_in,
                              void* d_out, int out_size, void* d_ws, size_t ws_size,
                              hipStream_t stream) {
    const float* seg_feat    = (const float*)d_in[0];
    const float* conv_weight = (const float*)d_in[1];
    const float* mask        = (const float*)d_in[2];
    const int*   ind         = (const int*)d_in[3];
    const float* target      = (const float*)d_in[4];
    float* out = (float*)d_out;

    uint32_t* fragtab  = (uint32_t*)d_ws;
    float*    red_base = (float*)d_ws + FRAG_U32;

    pack_frags<<<256, 64, 0, stream>>>(conv_weight, mask, ind, fragtab);
    seg_dice_main<<<NBLK, 256, 0, stream>>>(seg_feat, target, fragtab, red_base);
    seg_dice_final<<<1, 128, 0, stream>>>(red_base, out);
}